// Round 12
// baseline (139.312 us; speedup 1.0000x reference)
//
#include <hip/hip_runtime.h>
#include <hip/hip_bf16.h>

// EncoderBlock: B=4 S=2048 D=512 H=8 DK=64 DFF=2048, fp32 in/out, bf16 MFMA compute.
// Round 12: all GEMMs BN=128 (2:1 MFMA:LDS ratio), NBUF=2 everywhere;
// MODE1 epilogue generalized to BN=128; attn zero-seed micro-trim.

#define B_   4
#define S_   2048
#define D_   512
#define H_   8
#define DK_  64
#define DFF_ 2048
#define M_   (B_*S_)

typedef __attribute__((ext_vector_type(8))) short short8;
typedef __attribute__((ext_vector_type(4))) float f32x4;
typedef __attribute__((ext_vector_type(16))) float f32x16;

#define QSCALE 0.18033688011f   /* 0.125 * log2(e): softmax computed in exp2 domain */

#if __has_builtin(__builtin_amdgcn_exp2f)
#define EXP2(x) __builtin_amdgcn_exp2f(x)
#else
#define EXP2(x) exp2f(x)
#endif

#define GLOAD_LDS(gp, lp) __builtin_amdgcn_global_load_lds( \
    (const __attribute__((address_space(1))) void*)(gp),    \
    (__attribute__((address_space(3))) void*)(lp), 16, 0, 0)

#define WAITV(N) asm volatile("s_waitcnt vmcnt(" #N ")" ::: "memory")
#define BARRIER() __builtin_amdgcn_s_barrier()

__device__ inline unsigned short f2bf(float f) {
    union { float f; unsigned u; } v; v.f = f;
    unsigned r = v.u + 0x7fffu + ((v.u >> 16) & 1u);
    return (unsigned short)(r >> 16);
}

__device__ inline unsigned cvtpk_bf16(float a, float b) {
    unsigned r;
    asm("v_cvt_pk_bf16_f32 %0, %1, %2" : "=v"(r) : "v"(a), "v"(b));
    return r;
}

__device__ inline void permswap32(unsigned &x, unsigned &y) {
    asm volatile("v_permlane32_swap_b32 %0, %1" : "+v"(x), "+v"(y));
}

// ---- fused prep: weight transpose (6 weights) + bias/mask prep + LN1 ----
__global__ __launch_bounds__(256) void transT_kernel(
    const float* __restrict__ Wq, const float* __restrict__ Wk,
    const float* __restrict__ Wv, const float* __restrict__ Wo,
    const float* __restrict__ W1, const float* __restrict__ W2,
    const float* __restrict__ bq, const float* __restrict__ bk,
    const float* __restrict__ bv, const int* __restrict__ mask,
    float* __restrict__ qkvb, unsigned* __restrict__ mbits,
    short* __restrict__ dst,
    const float* __restrict__ x, const float* __restrict__ g1,
    const float* __restrict__ be1, short* __restrict__ xn) {
    const int id = blockIdx.x, t = threadIdx.x;
    if (id >= 769) {   // LN1: rows (id-769)*4 + w
        int w = t >> 6, l = t & 63;
        int row = (id - 769) * 4 + w;
        const float4* xr = (const float4*)(x + (size_t)row * D_);
        float4 a = xr[l * 2], b = xr[l * 2 + 1];
        float s = a.x + a.y + a.z + a.w + b.x + b.y + b.z + b.w;
        for (int off = 32; off > 0; off >>= 1) s += __shfl_xor(s, off);
        float mean = s * (1.f / 512.f);
        float e[8] = {a.x - mean, a.y - mean, a.z - mean, a.w - mean,
                      b.x - mean, b.y - mean, b.z - mean, b.w - mean};
        float vs = 0.f;
        #pragma unroll
        for (int i = 0; i < 8; i++) vs += e[i] * e[i];
        for (int off = 32; off > 0; off >>= 1) vs += __shfl_xor(vs, off);
        float scale = g1[0] / (sqrtf(vs * (1.f / 511.f)) + 1e-6f);
        float b0 = be1[0];
        union { short8 v; short s[8]; } o;
        #pragma unroll
        for (int i = 0; i < 8; i++) o.s[i] = (short)f2bf(e[i] * scale + b0);
        *(short8*)(xn + (size_t)row * D_ + l * 8) = o.v;
        return;
    }
    if (id == 768) {   // prep: fused QKV bias [bq*QSCALE|bk|bv] + mask bitmask
        for (int i = t; i < 1536; i += 256)
            qkvb[i] = (i < 512) ? bq[i] * QSCALE : (i < 1024) ? bk[i - 512] : bv[i - 1024];
        if (t < 128) {
            int b = t >> 5, tile = t & 31;
            const int* mr = mask + b * S_ + tile * 64;
            bool all1 = true;
            for (int u = 0; u < 64; u++) all1 &= (mr[u] != 0);
            unsigned long long bal = __ballot(all1);
            if ((t & 63) == 0) {
                mbits[(t >> 6) * 2]     = (unsigned)bal;
                mbits[(t >> 6) * 2 + 1] = (unsigned)(bal >> 32);
            }
        }
        return;
    }
    __shared__ float T[64][65];
    const float* src; short* d; int K, N, tk, tn;
    if (id < 256) {
        int m = id >> 6;
        src = (m == 0) ? Wq : (m == 1) ? Wk : (m == 2) ? Wv : Wo;
        d = dst + (size_t)m * 512 * 512; K = 512; N = 512;
        int j = id & 63; tk = j >> 3; tn = j & 7;
    } else if (id < 512) {
        src = W1; d = dst + (size_t)4 * 512 * 512; K = 512; N = 2048;
        int j = id - 256; tk = j >> 5; tn = j & 31;
    } else {
        src = W2; d = dst + (size_t)4 * 512 * 512 + 2048 * 512; K = 2048; N = 512;
        int j = id - 512; tk = j >> 3; tn = j & 7;
    }
    const int k0 = tk * 64, n0 = tn * 64;
    #pragma unroll
    for (int i = 0; i < 4; i++) {
        int r = i * 16 + (t >> 4), c4 = (t & 15) * 4;
        float4 v = *(const float4*)(src + (size_t)(k0 + r) * N + n0 + c4);
        T[r][c4] = v.x; T[r][c4 + 1] = v.y; T[r][c4 + 2] = v.z; T[r][c4 + 3] = v.w;
    }
    __syncthreads();
    #pragma unroll
    for (int p = 0; p < 2; p++) {
        int j = p * 256 + t, n = j >> 3, kc = (j & 7) * 8;
        union { short8 v; short s[8]; } o;
        #pragma unroll
        for (int u = 0; u < 8; u++) o.s[u] = (short)f2bf(T[kc + u][n]);
        *(short8*)(d + (size_t)(n0 + n) * K + k0 + kc) = o.v;
    }
}

// ---- LayerNorm (Bessel var, eps added to std), fp32 in -> bf16 out ----
__global__ __launch_bounds__(256) void ln_kernel(const float* __restrict__ x,
                                                 const float* __restrict__ g,
                                                 const float* __restrict__ be,
                                                 short* __restrict__ out) {
    int w = threadIdx.x >> 6, l = threadIdx.x & 63;
    int row = blockIdx.x * 4 + w;
    const float4* xr = (const float4*)(x + (size_t)row * D_);
    float4 a = xr[l * 2], b = xr[l * 2 + 1];
    float s = a.x + a.y + a.z + a.w + b.x + b.y + b.z + b.w;
    for (int off = 32; off > 0; off >>= 1) s += __shfl_xor(s, off);
    float mean = s * (1.f / 512.f);
    float e[8] = {a.x - mean, a.y - mean, a.z - mean, a.w - mean,
                  b.x - mean, b.y - mean, b.z - mean, b.w - mean};
    float vs = 0.f;
    #pragma unroll
    for (int i = 0; i < 8; i++) vs += e[i] * e[i];
    for (int off = 32; off > 0; off >>= 1) vs += __shfl_xor(vs, off);
    float scale = g[0] / (sqrtf(vs * (1.f / 511.f)) + 1e-6f);
    float b0 = be[0];
    union { short8 v; short s[8]; } o;
    #pragma unroll
    for (int i = 0; i < 8; i++) o.s[i] = (short)f2bf(e[i] * scale + b0);
    *(short8*)(out + (size_t)row * D_ + l * 8) = o.v;
}

// ---- GEMM: C = A[M,K](bf16) @ Bt[N,K](bf16)^T + bias, mfma_16x16x32 ----
// BM=128, BN=128, BK=64, 4 waves (2x2), wave-tile 64x64 (32 MFMA : 16 LDS reads
// per wave-kstep = 2:1). 2 LDS buffers, depth-1 counted vmcnt (r8-proven).
// MODE 0: fused QKV out (seg0: Q*QSCALE->[B,H,S,DK]; seg1: K; seg2: V->[B,H,DK,S])
// MODE 1: fp32 out = resid + acc + bias        (float4 via LDS transpose, BN=128)
// MODE 2: bf16 out = relu(acc + bias)          (short8 via LDS transpose)
template <int BN, int MODE>
__global__ __launch_bounds__(256, 2) void gemm_kernel(
    const short* __restrict__ A, const short* __restrict__ Bt,
    const float* __restrict__ bias, const float* __restrict__ resid,
    void* __restrict__ out, int M, int N, int K) {
    constexpr int NF = BN / 32;
    __shared__ __align__(16) short smem[2 * 128 * 64 + 2 * BN * 64];
    auto As = [&](int b) -> short* { return smem + b * 8192; };
    auto Bs = [&](int b) -> short* { return smem + 16384 + b * BN * 64; };
    const int t = threadIdx.x;
    const int w = t >> 6, l = t & 63;
    const int wm = w >> 1, wn = w & 1;
    const int lr = l & 15, lk = l >> 4;
    const int m0 = blockIdx.x * 128, n0 = blockIdx.y * BN;
    f32x4 acc[4][NF] = {};

    auto stage = [&](int buf, int k0) {
        #pragma unroll
        for (int p = 0; p < 4; p++) {           // A: 1024 chunks, 4/thread
            int id = p * 256 + t;
            int r = id >> 3, c = id & 7, cs = c ^ (r & 7);
            GLOAD_LDS(A + (size_t)(m0 + r) * K + k0 + cs * 8, As(buf) + (p * 256 + w * 64) * 8);
        }
        #pragma unroll
        for (int p = 0; p < BN / 32; p++) {     // B: BN*8 chunks
            int id = p * 256 + t;
            int r = id >> 3, c = id & 7, cs = c ^ (r & 7);
            GLOAD_LDS(Bt + (size_t)(n0 + r) * K + k0 + cs * 8, Bs(buf) + (p * 256 + w * 64) * 8);
        }
    };

    const int nk = K >> 6;
    stage(0, 0);

    for (int tk = 0; tk < nk; ++tk) {
        const int cur = tk & 1;
        if (tk + 1 < nk) {
            stage(cur ^ 1, (tk + 1) * 64);
            if constexpr (BN == 128) WAITV(8); else WAITV(6);   // cur's loads done
        } else WAITV(0);
        BARRIER();
        short8 af[4][2], bf[NF][2];
        #pragma unroll
        for (int f = 0; f < 4; f++) {
            int ra = wm * 64 + f * 16 + lr;
            #pragma unroll
            for (int kk = 0; kk < 2; kk++)
                af[f][kk] = *(const short8*)&As(cur)[ra * 64 + (((kk * 4 + lk) ^ (ra & 7)) << 3)];
        }
        #pragma unroll
        for (int f = 0; f < NF; f++) {
            int rb = wn * (BN / 2) + f * 16 + lr;
            #pragma unroll
            for (int kk = 0; kk < 2; kk++)
                bf[f][kk] = *(const short8*)&Bs(cur)[rb * 64 + (((kk * 4 + lk) ^ (rb & 7)) << 3)];
        }
        __builtin_amdgcn_s_setprio(1);
        #pragma unroll
        for (int kk = 0; kk < 2; kk++)
            #pragma unroll
            for (int mf = 0; mf < 4; mf++)
                #pragma unroll
                for (int nf = 0; nf < NF; nf++)
                    acc[mf][nf] = __builtin_amdgcn_mfma_f32_16x16x32_bf16(
                        af[mf][kk], bf[nf][kk], acc[mf][nf], 0, 0, 0);
        __builtin_amdgcn_s_setprio(0);
        BARRIER();   // all reads of cur done before next overwrite
    }

    if constexpr (MODE == 0) {
        const int seg = n0 >> 9;               // block-uniform
        if (seg < 2) {                         // Q/K: LDS transpose -> short8 stores
            unsigned short* E16 = (unsigned short*)smem;
            #pragma unroll
            for (int mf = 0; mf < 4; mf++)
                #pragma unroll
                for (int nf = 0; nf < NF; nf++) {
                    int n_loc = wn * (BN / 2) + nf * 16 + lr;
                    float bv = bias[n0 + n_loc];
                    int c = n_loc >> 3;
                    #pragma unroll
                    for (int i = 0; i < 4; i++) {
                        int m_loc = wm * 64 + mf * 16 + lk * 4 + i;
                        float val = acc[mf][nf][i];
                        if (seg == 0) val *= QSCALE;
                        E16[m_loc * 128 + ((c ^ (m_loc & 7)) << 3) + (n_loc & 7)] =
                            f2bf(val + bv);
                    }
                }
            BARRIER();
            unsigned short* ob = (unsigned short*)out + (size_t)seg * M_ * D_;
            #pragma unroll
            for (int pass = 0; pass < 8; pass++) {
                int fid = pass * 256 + t;      // 2048 short8s
                int row = fid >> 4, c = fid & 15;
                short8 v = *(short8*)&E16[row * 128 + ((c ^ (row & 7)) << 3)];
                int m = m0 + row, n = n0 + c * 8;
                int bb = m >> 11, sl = m & 2047, nl = n & 511;
                int h2 = nl >> 6, dk = nl & 63;
                *(short8*)&ob[(((size_t)(bb * 8 + h2) * 2048 + sl) << 6) + dk] = v;
            }
        } else {                               // V: 4 consecutive sl -> 8B store
            #pragma unroll
            for (int mf = 0; mf < 4; mf++) {
                #pragma unroll
                for (int nf = 0; nf < NF; nf++) {
                    int mb = m0 + wm * 64 + mf * 16 + lk * 4;
                    int n  = n0 + wn * (BN / 2) + nf * 16 + lr;
                    float bv = bias[n];
                    int bb = mb >> 11, sl = mb & 2047, nl = n & 511;
                    unsigned short* ob = (unsigned short*)out + (size_t)2 * M_ * D_;
                    uint2 pk;
                    pk.x = cvtpk_bf16(acc[mf][nf][0] + bv, acc[mf][nf][1] + bv);
                    pk.y = cvtpk_bf16(acc[mf][nf][2] + bv, acc[mf][nf][3] + bv);
                    *(uint2*)&ob[(((size_t)(bb * 8 + (nl >> 6)) * 64 + (nl & 63)) << 11) + sl] = pk;
                }
            }
        }
    } else if constexpr (MODE == 1) {          // LDS-transpose -> float4 out (BN generic)
        constexpr int SW = BN / 16 - 1;
        float* E = (float*)smem;               // [128][BN] floats (BN=128: 64KB exact)
        #pragma unroll
        for (int mf = 0; mf < 4; mf++)
            #pragma unroll
            for (int nf = 0; nf < NF; nf++) {
                int n_loc = wn * (BN / 2) + nf * 16 + lr;
                float bv = bias[n0 + n_loc];
                int c = n_loc >> 4;
                #pragma unroll
                for (int i = 0; i < 4; i++) {
                    int m_loc = wm * 64 + mf * 16 + lk * 4 + i;
                    E[m_loc * BN + ((c ^ (m_loc & SW)) << 4) + (n_loc & 15)] =
                        acc[mf][nf][i] + bv;
                }
            }
        BARRIER();
        #pragma unroll
        for (int pass = 0; pass < BN / 8; pass++) {
            int fid = pass * 256 + t;          // 128*(BN/4) float4s
            int row = fid / (BN / 4), c4 = fid & (BN / 4 - 1);
            int lc = c4 >> 2, j = c4 & 3;
            f32x4 v = *(f32x4*)&E[row * BN + ((lc ^ (row & SW)) << 4) + j * 4];
            int m = m0 + row, n = n0 + lc * 16 + j * 4;
            f32x4 rv = *(const f32x4*)&resid[(size_t)m * N + n];
            *(f32x4*)&((float*)out)[(size_t)m * N + n] = v + rv;
        }
    } else {                                   // MODE 2: LDS-transpose -> short8 out (BN=128)
        unsigned short* E16 = (unsigned short*)smem;
        #pragma unroll
        for (int mf = 0; mf < 4; mf++)
            #pragma unroll
            for (int nf = 0; nf < NF; nf++) {
                int n_loc = wn * (BN / 2) + nf * 16 + lr;
                float bv = bias[n0 + n_loc];
                int c = n_loc >> 3;
                #pragma unroll
                for (int i = 0; i < 4; i++) {
                    int m_loc = wm * 64 + mf * 16 + lk * 4 + i;
                    E16[m_loc * 128 + ((c ^ (m_loc & 7)) << 3) + (n_loc & 7)] =
                        f2bf(fmaxf(acc[mf][nf][i] + bv, 0.f));
                }
            }
        BARRIER();
        #pragma unroll
        for (int pass = 0; pass < 8; pass++) {
            int fid = pass * 256 + t;          // 2048 short8s
            int row = fid >> 4, c = fid & 15;
            short8 v = *(short8*)&E16[row * 128 + ((c ^ (row & 7)) << 3)];
            *(short8*)&((unsigned short*)out)[(size_t)(m0 + row) * N + n0 + c * 8] = v;
        }
    }
}

// ---- Flash attention (round-6/10 proven config: 47.0-47.2 us) ----
// Swapped-QK 32x32, fixed softmax max, 8-wave 2-way split-KV, 32 q/wave.
// KVBLK=32, 3 buffers/half, depth-2 prefetch with counted vmcnt (WAITV(2)).
// QK chain seeded from a hoisted zero vector (no per-tile acc re-zeroing).
__global__ __launch_bounds__(512, 4) void attn_kernel(
    const short* __restrict__ Q, const short* __restrict__ Kb,
    const short* __restrict__ Vt, const int* __restrict__ mask,
    const unsigned* __restrict__ mbits, unsigned short* __restrict__ O) {
    __shared__ __align__(16) short sm[24576];   // 48KB: [half][buf][K 2048|V 2048]
    const int t = threadIdx.x, w = t >> 6, l = t & 63;
    const int ql = l & 31, hi = l >> 5;
    const int wh = w >> 2, wl = w & 3;
    const int bh = blockIdx.x, b = bh >> 3, h = bh & 7;
    const int q = blockIdx.y * 128 + wl * 32 + ql;

    const short* qrow = Q + ((size_t)bh * S_ + q) * DK_;
    short8 qf[4];
    #pragma unroll
    for (int s = 0; s < 4; s++) qf[s] = *(const short8*)(qrow + s * 16 + hi * 8);

    const short* kg = Kb + (size_t)bh * S_ * DK_;
    const short* vg = Vt + (size_t)bh * DK_ * S_;
    const int* mrow = mask + b * S_;
    const unsigned mb = mbits[b];

    short* KH = sm + wh * 12288;   // this half's region (3 bufs x 4096 shorts)

    auto stage = [&](int buf, int kv0) {
        short* Kd = KH + buf * 4096;
        short* Vd = Kd + 2048;
        {   // K: rows = kv (32 x 128B), 1 gload/wave
            int r = wl * 8 + (l >> 3), c = l & 7, cs = c ^ (r & 7);
            GLOAD_LDS(kg + (size_t)(kv0 + r) * DK_ + cs * 8, &Kd[wl * 512]);
        }
        {   // V packed: 1 gload/wave
            int r = wl * 8 + (l >> 3), s = l & 7, c = s ^ (r & 7);
            int dk = r + 32 * (c >> 2), kvo = (c & 3) * 8;
            GLOAD_LDS(vg + (size_t)dk * S_ + kv0 + kvo, &Vd[wl * 512]);
        }
    };

    const f32x16 z16 = {};         // hoisted zeros: seeds each tile's QK chain
    f32x16 o_acc[2] = {};
    float la0 = 0.f, la1 = 0.f, la2 = 0.f, la3 = 0.f;

    stage(0, wh * 1024);
    stage(1, wh * 1024 + 32);
    WAITV(2);
    BARRIER();

    for (int tt = 0; tt < 32; ++tt) {
        const int cur = tt % 3;
        const int gt = wh * 32 + tt;
        if (tt + 2 < 32) stage((tt + 2) % 3, (gt + 2) * 32);
        const short* Ks = KH + cur * 4096;
        const short* Vs = Ks + 2048;

        // QK^T swapped: s_acc[r] = S2[k][q], k = gt*32 + (r&3)+8*(r>>2)+4*hi
        __builtin_amdgcn_s_setprio(1);
        short8 kf0 = *(const short8*)&Ks[ql * 64 + ((hi ^ (ql & 7)) << 3)];
        f32x16 s_acc = __builtin_amdgcn_mfma_f32_32x32x16_bf16(kf0, qf[0], z16, 0, 0, 0);
        #pragma unroll
        for (int s = 1; s < 4; s++) {
            short8 kf = *(const short8*)&Ks[ql * 64 + (((s * 2 + hi) ^ (ql & 7)) << 3)];
            s_acc = __builtin_amdgcn_mfma_f32_32x32x16_bf16(kf, qf[s], s_acc, 0, 0, 0);
        }
        __builtin_amdgcn_s_setprio(0);

        if (!((mb >> (gt >> 1)) & 1)) {   // slow path only on tiles with masked keys
            #pragma unroll
            for (int r = 0; r < 16; r++) {
                int k = gt * 32 + (r & 3) + 8 * (r >> 2) + 4 * hi;
                if (mrow[k] == 0) s_acc[r] = -1.4426950e9f;
            }
        }

        // p = exp2(s); partial row sums; pack to bf16 dwords
        float p[16];
        #pragma unroll
        for (int r = 0; r < 16; r++) p[r] = EXP2(s_acc[r]);
        #pragma unroll
        for (int r = 0; r < 16; r += 4) {
            la0 += p[r]; la1 += p[r + 1]; la2 += p[r + 2]; la3 += p[r + 3];
        }
        unsigned Dp[8];
        #pragma unroll
        for (int j = 0; j < 8; j++) Dp[j] = cvtpk_bf16(p[2 * j], p[2 * j + 1]);

        // PV: O^T[d][q] += V-tile * P
        #pragma unroll
        for (int s16 = 0; s16 < 2; s16++) {
            unsigned f0 = Dp[s16 * 4 + 0], f1 = Dp[s16 * 4 + 1];
            unsigned f2 = Dp[s16 * 4 + 2], f3 = Dp[s16 * 4 + 3];
            permswap32(f0, f2);
            permswap32(f1, f3);
            union { unsigned u[4]; short8 v; } pu;
            pu.u[0] = f0; pu.u[1] = f1; pu.u[2] = f2; pu.u[3] = f3;
            __builtin_amdgcn_s_setprio(1);
            #pragma unroll
            for (int dt = 0; dt < 2; dt++) {
                short8 vf = *(const short8*)&Vs[ql * 64 + (((dt * 4 + s16 * 2 + hi) ^ (ql & 7)) << 3)];
                o_acc[dt] = __builtin_amdgcn_mfma_f32_32x32x16_bf16(vf, pu.v, o_acc[dt], 0, 0, 0);
            }
            __builtin_amdgcn_s_setprio(0);
        }

        if (tt < 30) WAITV(2); else WAITV(0);
        BARRIER();
    }

    float l_part = (la0 + la1) + (la2 + la3);
    float* C = (float*)sm;
    f32x4* Cv = (f32x4*)sm;
    if (wh == 1) {
        #pragma unroll
        for (int j = 0; j < 8; j++) {
            f32x4 v;
            #pragma unroll
            for (int e = 0; e < 4; e++) v[e] = o_acc[j >> 2][(j & 3) * 4 + e];
            Cv[wl * 512 + j * 64 + l] = v;
        }
        C[8192 + wl * 64 + l] = l_part;
    }
    __syncthreads();
    if (wh == 0) {
        #pragma unroll
        for (int j = 0; j < 8; j++) {
            f32x4 v = Cv[wl * 512 + j * 64 + l];
            #pragma unroll
            for (int e = 0; e < 4; e++) o_acc[j >> 2][(j & 3) * 4 + e] += v[e];
        }
        l_part += C[8192 + wl * 64 + l];
        float linv = 1.f / (l_part + __shfl_xor(l_part, 32));
        unsigned short* orow = O + ((size_t)b * S_ + q) * D_ + h * 64;
        #pragma unroll
        for (int dt = 0; dt < 2; dt++)
            #pragma unroll
            for (int g = 0; g < 4; g++) {
                unsigned u0 = cvtpk_bf16(o_acc[dt][g * 4 + 0] * linv, o_acc[dt][g * 4 + 1] * linv);
                unsigned u1 = cvtpk_bf16(o_acc[dt][g * 4 + 2] * linv, o_acc[dt][g * 4 + 3] * linv);
                uint2 pk; pk.x = u0; pk.y = u1;
                *(uint2*)(orow + dt * 32 + 8 * g + 4 * hi) = pk;
            }
    }
}

extern "C" void kernel_launch(void* const* d_in, const int* in_sizes, int n_in,
                              void* d_out, int out_size, void* d_ws, size_t ws_size,
                              hipStream_t stream) {
    const float* x    = (const float*)d_in[0];
    const int*   mask = (const int*)d_in[1];
    const float* Wq = (const float*)d_in[2];  const float* bq  = (const float*)d_in[3];
    const float* Wk = (const float*)d_in[4];  const float* bk  = (const float*)d_in[5];
    const float* Wv = (const float*)d_in[6];  const float* bv  = (const float*)d_in[7];
    const float* Wo = (const float*)d_in[8];  const float* bo  = (const float*)d_in[9];
    const float* W1 = (const float*)d_in[10]; const float* b1  = (const float*)d_in[11];
    const float* W2 = (const float*)d_in[12]; const float* b2  = (const float*)d_in[13];
    const float* g1 = (const float*)d_in[14]; const float* be1 = (const float*)d_in[15];
    const float* g2 = (const float*)d_in[16]; const float* be2 = (const float*)d_in[17];

    // workspace layout (bf16 buffers as short*)
    short* WqT = (short*)d_ws;                 // [512,512] x4, then W1T, W2T (transT order)
    short* W1T = WqT + 4 * 512 * 512;
    short* W2T = W1T + 2048 * 512;
    short* xn  = W2T + 512 * 2048;             // [8192,512]
    short* Qb  = xn  + (size_t)M_ * D_;        // [B,H,S,DK] (pre-scaled), then K, then Vt
    short* Kbf = Qb  + (size_t)M_ * D_;
    short* Vtb = Kbf + (size_t)M_ * D_;
    short* Ob  = Vtb + (size_t)M_ * D_;        // attn out [8192,512]
    float* x2  = (float*)(Ob + (size_t)M_ * D_);
    float* qkvb = x2;                          // 1536 floats; dead before x2 is written
    unsigned* mbits = (unsigned*)(qkvb + 1536);// 4 words; read by attn before x2 write
    short* WoT = WqT + 3 * 512 * 512;
    short* Hb  = Qb;                           // FFN hidden reuses Q..O region [8192,2048]

    transT_kernel<<<769 + M_ / 4, 256, 0, stream>>>(Wq, Wk, Wv, Wo, W1, W2,
                                                    bq, bk, bv, mask, qkvb, mbits, WqT,
                                                    x, g1, be1, xn);

    // fused QKV projection: N=1536 (Wq,Wk,Wv contiguous in transT output)
    gemm_kernel<128, 0><<<dim3(64, 12), 256, 0, stream>>>(xn, WqT, qkvb, nullptr,
                                                          Qb, M_, 1536, 512);

    attn_kernel<<<dim3(B_ * H_, S_ / 128), 512, 0, stream>>>(Qb, Kbf, Vtb, mask, mbits,
                                                             (unsigned short*)Ob);

    gemm_kernel<128, 1><<<dim3(64, 4), 256, 0, stream>>>(Ob, WoT, bo, x, x2, M_, 512, 512);

    ln_kernel<<<M_ / 4, 256, 0, stream>>>(x2, g2, be2, xn);

    gemm_kernel<128, 2><<<dim3(64, 16), 256, 0, stream>>>(xn, W1T, b1, nullptr, Hb, M_, 2048, 512);
    gemm_kernel<128, 1><<<dim3(64, 4), 256, 0, stream>>>(Hb, W2T, b2, x2, (float*)d_out, M_, 512, 2048);
}

// Round 13
// 135.941 us; speedup vs baseline: 1.0248x; 1.0248x over previous
//
#include <hip/hip_runtime.h>
#include <hip/hip_bf16.h>

// EncoderBlock: B=4 S=2048 D=512 H=8 DK=64 DFF=2048, fp32 in/out, bf16 MFMA compute.
// Round 13: r10 GEMM stack (best: 136.6us) + attn intra-wave QK/softmax skew
// (T15-lite): QK[t+1] MFMA overlaps softmax[t] VALU; 4 LDS buffers, depth-3.

#define B_   4
#define S_   2048
#define D_   512
#define H_   8
#define DK_  64
#define DFF_ 2048
#define M_   (B_*S_)

typedef __attribute__((ext_vector_type(8))) short short8;
typedef __attribute__((ext_vector_type(4))) float f32x4;
typedef __attribute__((ext_vector_type(16))) float f32x16;

#define QSCALE 0.18033688011f   /* 0.125 * log2(e): softmax computed in exp2 domain */

#if __has_builtin(__builtin_amdgcn_exp2f)
#define EXP2(x) __builtin_amdgcn_exp2f(x)
#else
#define EXP2(x) exp2f(x)
#endif

#define GLOAD_LDS(gp, lp) __builtin_amdgcn_global_load_lds( \
    (const __attribute__((address_space(1))) void*)(gp),    \
    (__attribute__((address_space(3))) void*)(lp), 16, 0, 0)

#define WAITV(N) asm volatile("s_waitcnt vmcnt(" #N ")" ::: "memory")
#define BARRIER() __builtin_amdgcn_s_barrier()

__device__ inline unsigned short f2bf(float f) {
    union { float f; unsigned u; } v; v.f = f;
    unsigned r = v.u + 0x7fffu + ((v.u >> 16) & 1u);
    return (unsigned short)(r >> 16);
}

__device__ inline unsigned cvtpk_bf16(float a, float b) {
    unsigned r;
    asm("v_cvt_pk_bf16_f32 %0, %1, %2" : "=v"(r) : "v"(a), "v"(b));
    return r;
}

__device__ inline void permswap32(unsigned &x, unsigned &y) {
    asm volatile("v_permlane32_swap_b32 %0, %1" : "+v"(x), "+v"(y));
}

// ---- fused prep: weight transpose (6 weights) + bias/mask prep + LN1 ----
__global__ __launch_bounds__(256) void transT_kernel(
    const float* __restrict__ Wq, const float* __restrict__ Wk,
    const float* __restrict__ Wv, const float* __restrict__ Wo,
    const float* __restrict__ W1, const float* __restrict__ W2,
    const float* __restrict__ bq, const float* __restrict__ bk,
    const float* __restrict__ bv, const int* __restrict__ mask,
    float* __restrict__ qkvb, unsigned* __restrict__ mbits,
    short* __restrict__ dst,
    const float* __restrict__ x, const float* __restrict__ g1,
    const float* __restrict__ be1, short* __restrict__ xn) {
    const int id = blockIdx.x, t = threadIdx.x;
    if (id >= 769) {   // LN1: rows (id-769)*4 + w
        int w = t >> 6, l = t & 63;
        int row = (id - 769) * 4 + w;
        const float4* xr = (const float4*)(x + (size_t)row * D_);
        float4 a = xr[l * 2], b = xr[l * 2 + 1];
        float s = a.x + a.y + a.z + a.w + b.x + b.y + b.z + b.w;
        for (int off = 32; off > 0; off >>= 1) s += __shfl_xor(s, off);
        float mean = s * (1.f / 512.f);
        float e[8] = {a.x - mean, a.y - mean, a.z - mean, a.w - mean,
                      b.x - mean, b.y - mean, b.z - mean, b.w - mean};
        float vs = 0.f;
        #pragma unroll
        for (int i = 0; i < 8; i++) vs += e[i] * e[i];
        for (int off = 32; off > 0; off >>= 1) vs += __shfl_xor(vs, off);
        float scale = g1[0] / (sqrtf(vs * (1.f / 511.f)) + 1e-6f);
        float b0 = be1[0];
        union { short8 v; short s[8]; } o;
        #pragma unroll
        for (int i = 0; i < 8; i++) o.s[i] = (short)f2bf(e[i] * scale + b0);
        *(short8*)(xn + (size_t)row * D_ + l * 8) = o.v;
        return;
    }
    if (id == 768) {   // prep: fused QKV bias [bq*QSCALE|bk|bv] + mask bitmask
        for (int i = t; i < 1536; i += 256)
            qkvb[i] = (i < 512) ? bq[i] * QSCALE : (i < 1024) ? bk[i - 512] : bv[i - 1024];
        if (t < 128) {
            int b = t >> 5, tile = t & 31;
            const int* mr = mask + b * S_ + tile * 64;
            bool all1 = true;
            for (int u = 0; u < 64; u++) all1 &= (mr[u] != 0);
            unsigned long long bal = __ballot(all1);
            if ((t & 63) == 0) {
                mbits[(t >> 6) * 2]     = (unsigned)bal;
                mbits[(t >> 6) * 2 + 1] = (unsigned)(bal >> 32);
            }
        }
        return;
    }
    __shared__ float T[64][65];
    const float* src; short* d; int K, N, tk, tn;
    if (id < 256) {
        int m = id >> 6;
        src = (m == 0) ? Wq : (m == 1) ? Wk : (m == 2) ? Wv : Wo;
        d = dst + (size_t)m * 512 * 512; K = 512; N = 512;
        int j = id & 63; tk = j >> 3; tn = j & 7;
    } else if (id < 512) {
        src = W1; d = dst + (size_t)4 * 512 * 512; K = 512; N = 2048;
        int j = id - 256; tk = j >> 5; tn = j & 31;
    } else {
        src = W2; d = dst + (size_t)4 * 512 * 512 + 2048 * 512; K = 2048; N = 512;
        int j = id - 512; tk = j >> 3; tn = j & 7;
    }
    const int k0 = tk * 64, n0 = tn * 64;
    #pragma unroll
    for (int i = 0; i < 4; i++) {
        int r = i * 16 + (t >> 4), c4 = (t & 15) * 4;
        float4 v = *(const float4*)(src + (size_t)(k0 + r) * N + n0 + c4);
        T[r][c4] = v.x; T[r][c4 + 1] = v.y; T[r][c4 + 2] = v.z; T[r][c4 + 3] = v.w;
    }
    __syncthreads();
    #pragma unroll
    for (int p = 0; p < 2; p++) {
        int j = p * 256 + t, n = j >> 3, kc = (j & 7) * 8;
        union { short8 v; short s[8]; } o;
        #pragma unroll
        for (int u = 0; u < 8; u++) o.s[u] = (short)f2bf(T[kc + u][n]);
        *(short8*)(d + (size_t)(n0 + n) * K + k0 + kc) = o.v;
    }
}

// ---- LayerNorm (Bessel var, eps added to std), fp32 in -> bf16 out ----
__global__ __launch_bounds__(256) void ln_kernel(const float* __restrict__ x,
                                                 const float* __restrict__ g,
                                                 const float* __restrict__ be,
                                                 short* __restrict__ out) {
    int w = threadIdx.x >> 6, l = threadIdx.x & 63;
    int row = blockIdx.x * 4 + w;
    const float4* xr = (const float4*)(x + (size_t)row * D_);
    float4 a = xr[l * 2], b = xr[l * 2 + 1];
    float s = a.x + a.y + a.z + a.w + b.x + b.y + b.z + b.w;
    for (int off = 32; off > 0; off >>= 1) s += __shfl_xor(s, off);
    float mean = s * (1.f / 512.f);
    float e[8] = {a.x - mean, a.y - mean, a.z - mean, a.w - mean,
                  b.x - mean, b.y - mean, b.z - mean, b.w - mean};
    float vs = 0.f;
    #pragma unroll
    for (int i = 0; i < 8; i++) vs += e[i] * e[i];
    for (int off = 32; off > 0; off >>= 1) vs += __shfl_xor(vs, off);
    float scale = g[0] / (sqrtf(vs * (1.f / 511.f)) + 1e-6f);
    float b0 = be[0];
    union { short8 v; short s[8]; } o;
    #pragma unroll
    for (int i = 0; i < 8; i++) o.s[i] = (short)f2bf(e[i] * scale + b0);
    *(short8*)(out + (size_t)row * D_ + l * 8) = o.v;
}

// ---- GEMM: C = A[M,K](bf16) @ Bt[N,K](bf16)^T + bias, mfma_16x16x32 ----
// BM=128, BK=64, 4 waves (2x2), wave-tile 64x(BN/2). 2 LDS buffers, depth-1
// prefetch with COUNTED vmcnt. Coalesced epilogues. (round-10 proven config)
template <int BN, int MODE>
__global__ __launch_bounds__(256, 2) void gemm_kernel(
    const short* __restrict__ A, const short* __restrict__ Bt,
    const float* __restrict__ bias, const float* __restrict__ resid,
    void* __restrict__ out, int M, int N, int K) {
    constexpr int NF = BN / 32;
    __shared__ __align__(16) short smem[2 * 128 * 64 + 2 * BN * 64];
    auto As = [&](int b) -> short* { return smem + b * 8192; };
    auto Bs = [&](int b) -> short* { return smem + 16384 + b * BN * 64; };
    const int t = threadIdx.x;
    const int w = t >> 6, l = t & 63;
    const int wm = w >> 1, wn = w & 1;
    const int lr = l & 15, lk = l >> 4;
    const int m0 = blockIdx.x * 128, n0 = blockIdx.y * BN;
    f32x4 acc[4][NF] = {};

    auto stage = [&](int buf, int k0) {
        #pragma unroll
        for (int p = 0; p < 4; p++) {           // A: 1024 chunks, 4/thread
            int id = p * 256 + t;
            int r = id >> 3, c = id & 7, cs = c ^ (r & 7);
            GLOAD_LDS(A + (size_t)(m0 + r) * K + k0 + cs * 8, As(buf) + (p * 256 + w * 64) * 8);
        }
        #pragma unroll
        for (int p = 0; p < BN / 32; p++) {     // B: BN*8 chunks
            int id = p * 256 + t;
            int r = id >> 3, c = id & 7, cs = c ^ (r & 7);
            GLOAD_LDS(Bt + (size_t)(n0 + r) * K + k0 + cs * 8, Bs(buf) + (p * 256 + w * 64) * 8);
        }
    };

    const int nk = K >> 6;
    stage(0, 0);

    for (int tk = 0; tk < nk; ++tk) {
        const int cur = tk & 1;
        if (tk + 1 < nk) {
            stage(cur ^ 1, (tk + 1) * 64);
            if constexpr (BN == 128) WAITV(8); else WAITV(6);   // cur's loads done
        } else WAITV(0);
        BARRIER();
        short8 af[4][2], bf[NF][2];
        #pragma unroll
        for (int f = 0; f < 4; f++) {
            int ra = wm * 64 + f * 16 + lr;
            #pragma unroll
            for (int kk = 0; kk < 2; kk++)
                af[f][kk] = *(const short8*)&As(cur)[ra * 64 + (((kk * 4 + lk) ^ (ra & 7)) << 3)];
        }
        #pragma unroll
        for (int f = 0; f < NF; f++) {
            int rb = wn * (BN / 2) + f * 16 + lr;
            #pragma unroll
            for (int kk = 0; kk < 2; kk++)
                bf[f][kk] = *(const short8*)&Bs(cur)[rb * 64 + (((kk * 4 + lk) ^ (rb & 7)) << 3)];
        }
        __builtin_amdgcn_s_setprio(1);
        #pragma unroll
        for (int kk = 0; kk < 2; kk++)
            #pragma unroll
            for (int mf = 0; mf < 4; mf++)
                #pragma unroll
                for (int nf = 0; nf < NF; nf++)
                    acc[mf][nf] = __builtin_amdgcn_mfma_f32_16x16x32_bf16(
                        af[mf][kk], bf[nf][kk], acc[mf][nf], 0, 0, 0);
        __builtin_amdgcn_s_setprio(0);
        BARRIER();   // all reads of cur done before next overwrite
    }

    if constexpr (MODE == 0) {
        const int seg = n0 >> 9;               // block-uniform
        #pragma unroll
        for (int mf = 0; mf < 4; mf++) {
            #pragma unroll
            for (int nf = 0; nf < NF; nf++) {
                int mb = m0 + wm * 64 + mf * 16 + lk * 4;
                int n  = n0 + wn * (BN / 2) + nf * 16 + lr;
                float bv = bias[n];
                int bb = mb >> 11, sl = mb & 2047, nl = n & 511;
                unsigned short* ob = (unsigned short*)out + (size_t)seg * M_ * D_;
                float v[4];
                #pragma unroll
                for (int i = 0; i < 4; i++) {
                    float val = acc[mf][nf][i];
                    if (seg == 0) val *= QSCALE;
                    v[i] = val + bv;
                }
                if (seg < 2) {
                    #pragma unroll
                    for (int i = 0; i < 4; i++)
                        ob[(((size_t)(bb * 8 + (nl >> 6)) * 2048 + sl + i) << 6) + (nl & 63)] = f2bf(v[i]);
                } else {                        // V: 4 consecutive sl -> 8B store
                    uint2 pk;
                    pk.x = cvtpk_bf16(v[0], v[1]);
                    pk.y = cvtpk_bf16(v[2], v[3]);
                    *(uint2*)&ob[(((size_t)(bb * 8 + (nl >> 6)) * 64 + (nl & 63)) << 11) + sl] = pk;
                }
            }
        }
    } else if constexpr (MODE == 1) {          // LDS-transpose -> float4 out
        float* E = (float*)smem;
        #pragma unroll
        for (int mf = 0; mf < 4; mf++)
            #pragma unroll
            for (int nf = 0; nf < NF; nf++) {
                int n_loc = wn * (BN / 2) + nf * 16 + lr;
                float bv = bias[n0 + n_loc];
                int c = n_loc >> 4;
                #pragma unroll
                for (int i = 0; i < 4; i++) {
                    int m_loc = wm * 64 + mf * 16 + lk * 4 + i;
                    E[m_loc * 64 + ((c ^ (m_loc & 3)) << 4) + (n_loc & 15)] =
                        acc[mf][nf][i] + bv;
                }
            }
        BARRIER();
        #pragma unroll
        for (int pass = 0; pass < 8; pass++) {
            int fid = pass * 256 + t;          // 2048 float4s
            int row = fid >> 4, c4 = fid & 15;
            int lc = c4 >> 2, j = c4 & 3;
            f32x4 v = *(f32x4*)&E[row * 64 + (((lc ^ (row & 3))) << 4) + j * 4];
            int m = m0 + row, n = n0 + lc * 16 + j * 4;
            f32x4 rv = *(const f32x4*)&resid[(size_t)m * N + n];
            *(f32x4*)&((float*)out)[(size_t)m * N + n] = v + rv;
        }
    } else {                                   // MODE 2: LDS-transpose -> short8 out
        unsigned short* E16 = (unsigned short*)smem;
        #pragma unroll
        for (int mf = 0; mf < 4; mf++)
            #pragma unroll
            for (int nf = 0; nf < NF; nf++) {
                int n_loc = wn * (BN / 2) + nf * 16 + lr;
                float bv = bias[n0 + n_loc];
                int c = n_loc >> 3;
                #pragma unroll
                for (int i = 0; i < 4; i++) {
                    int m_loc = wm * 64 + mf * 16 + lk * 4 + i;
                    E16[m_loc * 128 + ((c ^ (m_loc & 7)) << 3) + (n_loc & 7)] =
                        f2bf(fmaxf(acc[mf][nf][i] + bv, 0.f));
                }
            }
        BARRIER();
        #pragma unroll
        for (int pass = 0; pass < 8; pass++) {
            int fid = pass * 256 + t;          // 2048 short8s
            int row = fid >> 4, c = fid & 15;
            short8 v = *(short8*)&E16[row * 128 + ((c ^ (row & 7)) << 3)];
            *(short8*)&((unsigned short*)out)[(size_t)(m0 + row) * N + n0 + c * 8] = v;
        }
    }
}

// ---- Flash attention: r6 structure + intra-wave QK/softmax skew (T15-lite) ----
// Swapped-QK 32x32, fixed softmax max, 8-wave 2-way split-KV, 32 q/wave.
// KVBLK=32, 4 buffers/half (64KB), depth-3 prefetch, counted vmcnt WAITV(2).
// Iteration tt: stage[tt+3] || QK[tt+1] (MFMA) || softmax[tt] (VALU) -> PV[tt].
// QK[tt+1] reads data staged at iter tt-2, covered by WAITV(2) at iter tt-1.
__global__ __launch_bounds__(512, 4) void attn_kernel(
    const short* __restrict__ Q, const short* __restrict__ Kb,
    const short* __restrict__ Vt, const int* __restrict__ mask,
    const unsigned* __restrict__ mbits, unsigned short* __restrict__ O) {
    __shared__ __align__(16) short sm[32768];   // 64KB: [half][4 bufs][K 2048|V 2048]
    const int t = threadIdx.x, w = t >> 6, l = t & 63;
    const int ql = l & 31, hi = l >> 5;
    const int wh = w >> 2, wl = w & 3;
    const int bh = blockIdx.x, b = bh >> 3, h = bh & 7;
    const int q = blockIdx.y * 128 + wl * 32 + ql;

    const short* qrow = Q + ((size_t)bh * S_ + q) * DK_;
    short8 qf[4];
    #pragma unroll
    for (int s = 0; s < 4; s++) qf[s] = *(const short8*)(qrow + s * 16 + hi * 8);

    const short* kg = Kb + (size_t)bh * S_ * DK_;
    const short* vg = Vt + (size_t)bh * DK_ * S_;
    const int* mrow = mask + b * S_;
    const unsigned mb = mbits[b];

    short* KH = sm + wh * 16384;   // this half's region (4 bufs x 4096 shorts)

    auto stage = [&](int buf, int kv0) {
        short* Kd = KH + buf * 4096;
        short* Vd = Kd + 2048;
        {   // K: rows = kv (32 x 128B), 1 gload/wave
            int r = wl * 8 + (l >> 3), c = l & 7, cs = c ^ (r & 7);
            GLOAD_LDS(kg + (size_t)(kv0 + r) * DK_ + cs * 8, &Kd[wl * 512]);
        }
        {   // V packed: 1 gload/wave
            int r = wl * 8 + (l >> 3), s = l & 7, c = s ^ (r & 7);
            int dk = r + 32 * (c >> 2), kvo = (c & 3) * 8;
            GLOAD_LDS(vg + (size_t)dk * S_ + kv0 + kvo, &Vd[wl * 512]);
        }
    };

    const f32x16 z16 = {};
    auto qk = [&](const short* Ks) {            // 4-deep MFMA chain, zero-seeded
        short8 kf0 = *(const short8*)&Ks[ql * 64 + ((hi ^ (ql & 7)) << 3)];
        f32x16 s = __builtin_amdgcn_mfma_f32_32x32x16_bf16(kf0, qf[0], z16, 0, 0, 0);
        #pragma unroll
        for (int ss = 1; ss < 4; ss++) {
            short8 kf = *(const short8*)&Ks[ql * 64 + (((ss * 2 + hi) ^ (ql & 7)) << 3)];
            s = __builtin_amdgcn_mfma_f32_32x32x16_bf16(kf, qf[ss], s, 0, 0, 0);
        }
        return s;
    };

    f32x16 o_acc[2] = {};
    float la0 = 0.f, la1 = 0.f, la2 = 0.f, la3 = 0.f;

    stage(0, wh * 1024);
    stage(1, wh * 1024 + 32);
    stage(2, wh * 1024 + 64);
    WAITV(2);                      // tiles 0,1 landed (tile 2 may be in flight)
    BARRIER();

    f32x16 s_cur = qk(KH);         // tile 0 scores

    for (int tt = 0; tt < 32; ++tt) {
        const int cur = tt & 3;
        const int gt = wh * 32 + tt;
        if (tt + 3 < 32) stage((tt + 3) & 3, (gt + 3) * 32);

        // QK for tile tt+1 (off critical path; overlaps softmax[tt] below)
        f32x16 s_next;
        if (tt + 1 < 32) s_next = qk(KH + ((tt + 1) & 3) * 4096);

        if (!((mb >> (gt >> 1)) & 1)) {   // slow path only on tiles with masked keys
            #pragma unroll
            for (int r = 0; r < 16; r++) {
                int k = gt * 32 + (r & 3) + 8 * (r >> 2) + 4 * hi;
                if (mrow[k] == 0) s_cur[r] = -1.4426950e9f;
            }
        }

        // p = exp2(s); partial row sums; pack to bf16 dwords
        float p[16];
        #pragma unroll
        for (int r = 0; r < 16; r++) p[r] = EXP2(s_cur[r]);
        #pragma unroll
        for (int r = 0; r < 16; r += 4) {
            la0 += p[r]; la1 += p[r + 1]; la2 += p[r + 2]; la3 += p[r + 3];
        }
        unsigned Dp[8];
        #pragma unroll
        for (int j = 0; j < 8; j++) Dp[j] = cvtpk_bf16(p[2 * j], p[2 * j + 1]);

        // PV: O^T[d][q] += V-tile * P
        const short* Vs = KH + cur * 4096 + 2048;
        #pragma unroll
        for (int s16 = 0; s16 < 2; s16++) {
            unsigned f0 = Dp[s16 * 4 + 0], f1 = Dp[s16 * 4 + 1];
            unsigned f2 = Dp[s16 * 4 + 2], f3 = Dp[s16 * 4 + 3];
            permswap32(f0, f2);
            permswap32(f1, f3);
            union { unsigned u[4]; short8 v; } pu;
            pu.u[0] = f0; pu.u[1] = f1; pu.u[2] = f2; pu.u[3] = f3;
            __builtin_amdgcn_s_setprio(1);
            #pragma unroll
            for (int dt = 0; dt < 2; dt++) {
                short8 vf = *(const short8*)&Vs[ql * 64 + (((dt * 4 + s16 * 2 + hi) ^ (ql & 7)) << 3)];
                o_acc[dt] = __builtin_amdgcn_mfma_f32_32x32x16_bf16(vf, pu.v, o_acc[dt], 0, 0, 0);
            }
            __builtin_amdgcn_s_setprio(0);
        }

        s_cur = s_next;
        if (tt < 29) WAITV(2); else WAITV(0);
        BARRIER();
    }

    float l_part = (la0 + la1) + (la2 + la3);
    float* C = (float*)sm;
    f32x4* Cv = (f32x4*)sm;
    if (wh == 1) {
        #pragma unroll
        for (int j = 0; j < 8; j++) {
            f32x4 v;
            #pragma unroll
            for (int e = 0; e < 4; e++) v[e] = o_acc[j >> 2][(j & 3) * 4 + e];
            Cv[wl * 512 + j * 64 + l] = v;
        }
        C[8192 + wl * 64 + l] = l_part;
    }
    __syncthreads();
    if (wh == 0) {
        #pragma unroll
        for (int j = 0; j < 8; j++) {
            f32x4 v = Cv[wl * 512 + j * 64 + l];
            #pragma unroll
            for (int e = 0; e < 4; e++) o_acc[j >> 2][(j & 3) * 4 + e] += v[e];
        }
        l_part += C[8192 + wl * 64 + l];
        float linv = 1.f / (l_part + __shfl_xor(l_part, 32));
        unsigned short* orow = O + ((size_t)b * S_ + q) * D_ + h * 64;
        #pragma unroll
        for (int dt = 0; dt < 2; dt++)
            #pragma unroll
            for (int g = 0; g < 4; g++) {
                unsigned u0 = cvtpk_bf16(o_acc[dt][g * 4 + 0] * linv, o_acc[dt][g * 4 + 1] * linv);
                unsigned u1 = cvtpk_bf16(o_acc[dt][g * 4 + 2] * linv, o_acc[dt][g * 4 + 3] * linv);
                uint2 pk; pk.x = u0; pk.y = u1;
                *(uint2*)(orow + dt * 32 + 8 * g + 4 * hi) = pk;
            }
    }
}

extern "C" void kernel_launch(void* const* d_in, const int* in_sizes, int n_in,
                              void* d_out, int out_size, void* d_ws, size_t ws_size,
                              hipStream_t stream) {
    const float* x    = (const float*)d_in[0];
    const int*   mask = (const int*)d_in[1];
    const float* Wq = (const float*)d_in[2];  const float* bq  = (const float*)d_in[3];
    const float* Wk = (const float*)d_in[4];  const float* bk  = (const float*)d_in[5];
    const float* Wv = (const float*)d_in[6];  const float* bv  = (const float*)d_in[7];
    const float* Wo = (const float*)d_in[8];  const float* bo  = (const float*)d_in[9];
    const float* W1 = (const float*)d_in[10]; const float* b1  = (const float*)d_in[11];
    const float* W2 = (const float*)d_in[12]; const float* b2  = (const float*)d_in[13];
    const float* g1 = (const float*)d_in[14]; const float* be1 = (const float*)d_in[15];
    const float* g2 = (const float*)d_in[16]; const float* be2 = (const float*)d_in[17];

    // workspace layout (bf16 buffers as short*)
    short* WqT = (short*)d_ws;                 // [512,512] x4, then W1T, W2T (transT order)
    short* W1T = WqT + 4 * 512 * 512;
    short* W2T = W1T + 2048 * 512;
    short* xn  = W2T + 512 * 2048;             // [8192,512]
    short* Qb  = xn  + (size_t)M_ * D_;        // [B,H,S,DK] (pre-scaled), then K, then Vt
    short* Kbf = Qb  + (size_t)M_ * D_;
    short* Vtb = Kbf + (size_t)M_ * D_;
    short* Ob  = Vtb + (size_t)M_ * D_;        // attn out [8192,512]
    float* x2  = (float*)(Ob + (size_t)M_ * D_);
    float* qkvb = x2;                          // 1536 floats; dead before x2 is written
    unsigned* mbits = (unsigned*)(qkvb + 1536);// 4 words; read by attn before x2 write
    short* WoT = WqT + 3 * 512 * 512;
    short* Hb  = Qb;                           // FFN hidden reuses Q..O region [8192,2048]

    transT_kernel<<<769 + M_ / 4, 256, 0, stream>>>(Wq, Wk, Wv, Wo, W1, W2,
                                                    bq, bk, bv, mask, qkvb, mbits, WqT,
                                                    x, g1, be1, xn);

    // fused QKV projection: N=1536 (Wq,Wk,Wv contiguous in transT output)
    gemm_kernel<128, 0><<<dim3(64, 12), 256, 0, stream>>>(xn, WqT, qkvb, nullptr,
                                                          Qb, M_, 1536, 512);

    attn_kernel<<<dim3(B_ * H_, S_ / 128), 512, 0, stream>>>(Qb, Kbf, Vtb, mask, mbits,
                                                             (unsigned short*)Ob);

    gemm_kernel<64, 1><<<dim3(64, 8), 256, 0, stream>>>(Ob, WoT, bo, x, x2, M_, 512, 512);

    ln_kernel<<<M_ / 4, 256, 0, stream>>>(x2, g2, be2, xn);

    gemm_kernel<128, 2><<<dim3(64, 16), 256, 0, stream>>>(xn, W1T, b1, nullptr, Hb, M_, 2048, 512);
    gemm_kernel<64, 1><<<dim3(64, 8), 256, 0, stream>>>(Hb, W2T, b2, x2, (float*)d_out, M_, 512, 2048);
}